// Round 11
// baseline (417.171 us; speedup 1.0000x reference)
//
#include <hip/hip_runtime.h>
#include <hip/hip_bf16.h>

#define D 64
#define RB 8                      // 256-node fine ranges
#define RSZ 256
#define MAXB 1024                 // max buckets supported (need 782)
#define CH 4096                   // edges staged per scatter block
#define SCT 1024                  // scatter block threads
#define GCH 4096                  // entries per gather sort-chunk (32KB LDS)

// ---------------- fallback: round-1 atomic kernel (known-good) ----------------
__global__ __launch_bounds__(256) void spmm_atomic_kernel(
    const int* __restrict__ idx, const float* __restrict__ wgt,
    const float* __restrict__ x, float* __restrict__ out, int E, int col_off) {
    const int lane   = threadIdx.x & 63;
    const int wave   = (blockIdx.x * blockDim.x + threadIdx.x) >> 6;
    const int nwaves = (gridDim.x * blockDim.x) >> 6;
    const int chunk = (E + nwaves - 1) / nwaves;
    int e0 = wave * chunk, e1 = min(e0 + chunk, E);
    for (int e = e0; e < e1; ++e) {
        const int dst = idx[e], src = idx[E + e];
        const float v = wgt[e] * x[src * D + lane];
        atomicAdd(&out[dst * 2 * D + col_off + lane], v);
    }
}

// ---------------- fused prep: x->bf16 cvt (blocks < cvtBlocks) + dst hist ----
__global__ __launch_bounds__(256) void prep_kernel(
    const float* __restrict__ x, unsigned short* __restrict__ xb, int total4,
    const int* __restrict__ ei1, const int* __restrict__ ei2,
    int E1, int E2, int nranges, int nbc, int* __restrict__ counts,
    int cvtBlocks) {
    __shared__ int lhist[MAXB];
    if ((int)blockIdx.x < cvtBlocks) {
        int i = blockIdx.x * 256 + threadIdx.x;
        if (i < total4) {
            float4 v = ((const float4*)x)[i];
            ushort4 o;
            unsigned u;
            u = __float_as_uint(v.x); o.x = (unsigned short)((u + 0x7FFF + ((u >> 16) & 1)) >> 16);
            u = __float_as_uint(v.y); o.y = (unsigned short)((u + 0x7FFF + ((u >> 16) & 1)) >> 16);
            u = __float_as_uint(v.z); o.z = (unsigned short)((u + 0x7FFF + ((u >> 16) & 1)) >> 16);
            u = __float_as_uint(v.w); o.w = (unsigned short)((u + 0x7FFF + ((u >> 16) & 1)) >> 16);
            ((ushort4*)xb)[i] = o;
        }
        return;
    }
    const int hb = blockIdx.x - cvtBlocks;
    const int nhb = gridDim.x - cvtBlocks;
    const int t = threadIdx.x;
    for (int i = t; i < nbc; i += 256) lhist[i] = 0;
    __syncthreads();
    const int Etot = E1 + E2;
    for (int e = hb * 256 + t; e < Etot; e += nhb * 256) {
        int b = (e < E1) ? (ei1[e] >> RB) : (nranges + (ei2[e - E1] >> RB));
        atomicAdd(&lhist[b], 1);
    }
    __syncthreads();
    for (int i = t; i < nbc; i += 256)
        if (lhist[i]) atomicAdd(&counts[i], lhist[i]);
}

// ---------------- bucketed path ----------------
// bucket id (hop-major): b = hop*nranges + (dst >> RB); payload dl = dst & 255
__device__ __forceinline__ void decode_edge(
    int e, const int* __restrict__ ei1, const float* __restrict__ ew1,
    const int* __restrict__ ei2, const float* __restrict__ ew2,
    int E1, int E2, int nranges, int& b, int& src, float& w, int& dl) {
    int dst;
    if (e < E1) { dst = ei1[e]; src = ei1[E1 + e]; w = ew1[e]; b = dst >> RB; }
    else { int f = e - E1; dst = ei2[f]; src = ei2[E2 + f]; w = ew2[f];
           b = nranges + (dst >> RB); }
    dl = dst & (RSZ - 1);
}

// single block (1024 threads): exclusive scan counts[0..nbc) -> starts, cursor;
// starts[nbc] = total
__global__ __launch_bounds__(1024) void scan_kernel(
    const int* __restrict__ counts, int nbc,
    int* __restrict__ starts, int* __restrict__ cursor) {
    __shared__ int lds[1024];
    const int t = threadIdx.x;
    int v = (t < nbc) ? counts[t] : 0;
    lds[t] = v;
    __syncthreads();
    for (int off = 1; off < 1024; off <<= 1) {
        int add = (t >= off) ? lds[t - off] : 0;
        __syncthreads();
        lds[t] += add;
        __syncthreads();
    }
    if (t < nbc) { starts[t] = lds[t] - v; cursor[t] = lds[t] - v; }
    if (t == nbc - 1) starts[nbc] = lds[t];   // total
}

// staged scatter: CH edges/block; decode ONCE into regs; LDS-bin by bucket;
// reserve contiguous span; run-wise line-pure copy-out
__global__ __launch_bounds__(1024) void scatter_kernel(
    const int* __restrict__ ei1, const float* __restrict__ ew1,
    const int* __restrict__ ei2, const float* __restrict__ ew2,
    int E1, int E2, int nranges, int nbc,
    int* __restrict__ cursor, int2* __restrict__ entries) {
    __shared__ int lstart[MAXB];
    __shared__ int lcur[MAXB];
    __shared__ int gbase[MAXB];
    __shared__ int2 ebuf[CH];
    __shared__ unsigned short ebkt[CH];

    const int t = threadIdx.x;
    const int Etot = E1 + E2;
    const int c0 = blockIdx.x * CH;
    const int cnt = min(CH, Etot - c0);

    // decode once into registers (4 edges/thread, static-indexed)
    int   eb[4], epk[4];
    float ewt[4];
#pragma unroll
    for (int i = 0; i < 4; ++i) {
        const int idx = t + i * SCT;
        eb[i] = 0; epk[i] = 0; ewt[i] = 0.f;
        if (idx < cnt) {
            int b, src, dl; float w;
            decode_edge(c0 + idx, ei1, ew1, ei2, ew2, E1, E2, nranges, b, src, w, dl);
            eb[i]  = b;
            epk[i] = src | (dl << 17);
            ewt[i] = w;
        }
    }

    for (int i = t; i < nbc; i += SCT) lcur[i] = 0;
    __syncthreads();
#pragma unroll
    for (int i = 0; i < 4; ++i) {
        const int idx = t + i * SCT;
        if (idx < cnt) atomicAdd(&lcur[eb[i]], 1);
    }
    __syncthreads();
    int v = (t < nbc) ? lcur[t] : 0;
    lstart[t] = v;
    __syncthreads();
    for (int off = 1; off < SCT; off <<= 1) {
        int add = (t >= off) ? lstart[t - off] : 0;
        __syncthreads();
        lstart[t] += add;
        __syncthreads();
    }
    int ex = lstart[t] - v;
    __syncthreads();
    if (t < nbc) {
        lstart[t] = ex;
        lcur[t]   = ex;
        gbase[t]  = v ? atomicAdd(&cursor[t], v) : 0;
    }
    __syncthreads();
#pragma unroll
    for (int i = 0; i < 4; ++i) {
        const int idx = t + i * SCT;
        if (idx < cnt) {
            int pos = atomicAdd(&lcur[eb[i]], 1);
            ebuf[pos] = make_int2(epk[i], __float_as_int(ewt[i]));
            ebkt[pos] = (unsigned short)eb[i];
        }
    }
    __syncthreads();
    for (int i = t; i < cnt; i += SCT) {
        int b = ebkt[i];
        entries[gbase[b] + (i - lstart[b])] = ebuf[i];
    }
}

// gather: one block per bucket. Per 4096-entry chunk: LDS counting-sort by dl,
// then wave wv accumulates nodes [16wv,16wv+16) into 16 static VGPRs.
// Inner loop: r7's proven single-entry form, unroll 8 -> 8 independent
// ds_read+global_load chains in flight per wave (latency-bound regime).
__global__ __launch_bounds__(1024, 8) void gather_kernel(
    const int2* __restrict__ entries, const int* __restrict__ starts,
    const unsigned short* __restrict__ xb, float* __restrict__ out,
    int N, int nranges) {
    __shared__ int2 sbuf[GCH];      // 32 KB sorted chunk
    __shared__ int shist[RSZ];
    __shared__ int sstart[RSZ];
    __shared__ int scur[RSZ];

    const int t    = threadIdx.x;
    const int lane = t & 63;
    const int wv   = t >> 6;        // 0..15
    // schedule heavy hop-2 buckets first
    const int c    = (blockIdx.x < nranges) ? (nranges + blockIdx.x)
                                            : (blockIdx.x - nranges);
    const int hop  = (c >= nranges) ? 1 : 0;
    const int r0   = (c - hop * nranges) << RB;

    const int s = starts[c];
    const int e = starts[c + 1];
    const unsigned short* xbl = xb + lane;   // lane-constant base

    float acc[16];
#pragma unroll
    for (int i = 0; i < 16; ++i) acc[i] = 0.f;

    for (int cb = s; cb < e; cb += GCH) {
        const int cnt = min(GCH, e - cb);
        if (t < RSZ) shist[t] = 0;
        __syncthreads();

        int2 ent[4];
#pragma unroll
        for (int i = 0; i < 4; ++i) {
            const int idx = t + i * 1024;
            if (idx < cnt) {
                ent[i] = entries[cb + idx];
                atomicAdd(&shist[(ent[i].x >> 17) & (RSZ - 1)], 1);
            }
        }
        __syncthreads();

        if (t < RSZ) sstart[t] = shist[t];
        __syncthreads();
        for (int off = 1; off < RSZ; off <<= 1) {
            int v = 0;
            if (t < RSZ && t >= off) v = sstart[t - off];
            __syncthreads();
            if (t < RSZ) sstart[t] += v;
            __syncthreads();
        }
        if (t < RSZ) { int ex = sstart[t] - shist[t]; sstart[t] = ex; scur[t] = ex; }
        __syncthreads();

#pragma unroll
        for (int i = 0; i < 4; ++i) {
            const int idx = t + i * 1024;
            if (idx < cnt) {
                int pos = atomicAdd(&scur[(ent[i].x >> 17) & (RSZ - 1)], 1);
                sbuf[pos] = ent[i];
            }
        }
        __syncthreads();

        // per-wave gather: dense sorted runs, register accumulation
#pragma unroll
        for (int nl = 0; nl < 16; ++nl) {
            const int dl = (wv << 4) + nl;
            const int js = sstart[dl];
            const int je = js + shist[dl];
            float a = acc[nl];
#pragma unroll 8
            for (int j = js; j < je; ++j) {
                const int2 q  = sbuf[j];               // uniform addr: broadcast
                const float w = __int_as_float(q.y);
                const int src = q.x & 0x1FFFF;
                const unsigned xv = xbl[src * D];      // coalesced 128B row
                a += w * __uint_as_float(xv << 16);    // bf16 -> f32 = shl 16
            }
            acc[nl] = a;
        }
        __syncthreads();   // protect sbuf/shist before next chunk
    }

#pragma unroll
    for (int nl = 0; nl < 16; ++nl) {
        const int node = r0 + (wv << 4) + nl;
        if (node < N) out[node * 2 * D + hop * D + lane] = acc[nl];
    }
}

extern "C" void kernel_launch(void* const* d_in, const int* in_sizes, int n_in,
                              void* d_out, int out_size, void* d_ws, size_t ws_size,
                              hipStream_t stream) {
    const float* x   = (const float*)d_in[0];
    const int*   ei1 = (const int*)d_in[1];
    const float* ew1 = (const float*)d_in[2];
    const int*   ei2 = (const int*)d_in[3];
    const float* ew2 = (const float*)d_in[4];

    const int E1 = in_sizes[2];
    const int E2 = in_sizes[4];
    const int N  = in_sizes[0] / D;
    const int Etot = E1 + E2;
    const int nranges = (N + RSZ - 1) >> RB;
    const int nbc = 2 * nranges;     // hop-major buckets (need 782)

    float* out = (float*)d_out;

    // ws layout: entries [Etot int2] | xb [N*D ushort] | counts | starts | cursor
    size_t off_entries = 0;
    size_t off_xb      = off_entries + (size_t)Etot * sizeof(int2);
    size_t off_counts  = off_xb + (((size_t)N * D * sizeof(unsigned short) + 15) & ~15ull);
    size_t off_starts  = off_counts + (size_t)nbc * sizeof(int);
    size_t off_cursor  = off_starts + (size_t)(nbc + 1) * sizeof(int);
    size_t needed      = off_cursor + (size_t)nbc * sizeof(int);

    if (ws_size < needed || nbc > MAXB || N > (1 << 17) || (N * D) % 4 != 0) {
        hipMemsetAsync(d_out, 0, (size_t)out_size * sizeof(float), stream);
        spmm_atomic_kernel<<<2048, 256, 0, stream>>>(ei1, ew1, x, out, E1, 0);
        spmm_atomic_kernel<<<2048, 256, 0, stream>>>(ei2, ew2, x, out, E2, D);
        return;
    }

    char* ws = (char*)d_ws;
    int2*           entries = (int2*)(ws + off_entries);
    unsigned short* xbuf    = (unsigned short*)(ws + off_xb);
    int*            counts  = (int*)(ws + off_counts);
    int*            starts  = (int*)(ws + off_starts);
    int*            cursor  = (int*)(ws + off_cursor);

    hipMemsetAsync(counts, 0, (size_t)nbc * sizeof(int), stream);

    const int total4 = (N * D) / 4;
    const int cvtBlocks = (total4 + 255) / 256;
    prep_kernel<<<cvtBlocks + 1024, 256, 0, stream>>>(
        x, xbuf, total4, ei1, ei2, E1, E2, nranges, nbc, counts, cvtBlocks);
    scan_kernel<<<1, 1024, 0, stream>>>(counts, nbc, starts, cursor);
    const int nchunks = (Etot + CH - 1) / CH;
    scatter_kernel<<<nchunks, SCT, 0, stream>>>(ei1, ew1, ei2, ew2, E1, E2,
                                                nranges, nbc, cursor, entries);
    gather_kernel<<<nbc, 1024, 0, stream>>>(entries, starts, xbuf, out, N, nranges);
}

// Round 12
// 321.732 us; speedup vs baseline: 1.2966x; 1.2966x over previous
//
#include <hip/hip_runtime.h>
#include <hip/hip_bf16.h>

#define D 64
#define RB 8                      // 256-node fine ranges
#define RSZ 256
#define MAXB 1024                 // max buckets supported (need 782)
#define CH 4096                   // edges staged per scatter block
#define SCT 1024                  // scatter block threads
#define GCH 4096                  // entries per gather sort-chunk (32KB LDS)

// ---------------- fallback: round-1 atomic kernel (known-good) ----------------
__global__ __launch_bounds__(256) void spmm_atomic_kernel(
    const int* __restrict__ idx, const float* __restrict__ wgt,
    const float* __restrict__ x, float* __restrict__ out, int E, int col_off) {
    const int lane   = threadIdx.x & 63;
    const int wave   = (blockIdx.x * blockDim.x + threadIdx.x) >> 6;
    const int nwaves = (gridDim.x * blockDim.x) >> 6;
    const int chunk = (E + nwaves - 1) / nwaves;
    int e0 = wave * chunk, e1 = min(e0 + chunk, E);
    for (int e = e0; e < e1; ++e) {
        const int dst = idx[e], src = idx[E + e];
        const float v = wgt[e] * x[src * D + lane];
        atomicAdd(&out[dst * 2 * D + col_off + lane], v);
    }
}

// ---------------- fused prep: x->bf16 cvt (blocks < cvtBlocks) + dst hist ----
__global__ __launch_bounds__(256) void prep_kernel(
    const float* __restrict__ x, unsigned short* __restrict__ xb, int total4,
    const int* __restrict__ ei1, const int* __restrict__ ei2,
    int E1, int E2, int nranges, int nbc, int* __restrict__ counts,
    int cvtBlocks) {
    __shared__ int lhist[MAXB];
    if ((int)blockIdx.x < cvtBlocks) {
        int i = blockIdx.x * 256 + threadIdx.x;
        if (i < total4) {
            float4 v = ((const float4*)x)[i];
            ushort4 o;
            unsigned u;
            u = __float_as_uint(v.x); o.x = (unsigned short)((u + 0x7FFF + ((u >> 16) & 1)) >> 16);
            u = __float_as_uint(v.y); o.y = (unsigned short)((u + 0x7FFF + ((u >> 16) & 1)) >> 16);
            u = __float_as_uint(v.z); o.z = (unsigned short)((u + 0x7FFF + ((u >> 16) & 1)) >> 16);
            u = __float_as_uint(v.w); o.w = (unsigned short)((u + 0x7FFF + ((u >> 16) & 1)) >> 16);
            ((ushort4*)xb)[i] = o;
        }
        return;
    }
    const int hb = blockIdx.x - cvtBlocks;
    const int nhb = gridDim.x - cvtBlocks;
    const int t = threadIdx.x;
    for (int i = t; i < nbc; i += 256) lhist[i] = 0;
    __syncthreads();
    const int Etot = E1 + E2;
    for (int e = hb * 256 + t; e < Etot; e += nhb * 256) {
        int b = (e < E1) ? (ei1[e] >> RB) : (nranges + (ei2[e - E1] >> RB));
        atomicAdd(&lhist[b], 1);
    }
    __syncthreads();
    for (int i = t; i < nbc; i += 256)
        if (lhist[i]) atomicAdd(&counts[i], lhist[i]);
}

// ---------------- bucketed path ----------------
// bucket id (hop-major): b = hop*nranges + (dst >> RB); payload dl = dst & 255
__device__ __forceinline__ void decode_edge(
    int e, const int* __restrict__ ei1, const float* __restrict__ ew1,
    const int* __restrict__ ei2, const float* __restrict__ ew2,
    int E1, int E2, int nranges, int& b, int& src, float& w, int& dl) {
    int dst;
    if (e < E1) { dst = ei1[e]; src = ei1[E1 + e]; w = ew1[e]; b = dst >> RB; }
    else { int f = e - E1; dst = ei2[f]; src = ei2[E2 + f]; w = ew2[f];
           b = nranges + (dst >> RB); }
    dl = dst & (RSZ - 1);
}

// single block (1024 threads): exclusive scan counts[0..nbc) -> starts, cursor;
// starts[nbc] = total
__global__ __launch_bounds__(1024) void scan_kernel(
    const int* __restrict__ counts, int nbc,
    int* __restrict__ starts, int* __restrict__ cursor) {
    __shared__ int lds[1024];
    const int t = threadIdx.x;
    int v = (t < nbc) ? counts[t] : 0;
    lds[t] = v;
    __syncthreads();
    for (int off = 1; off < 1024; off <<= 1) {
        int add = (t >= off) ? lds[t - off] : 0;
        __syncthreads();
        lds[t] += add;
        __syncthreads();
    }
    if (t < nbc) { starts[t] = lds[t] - v; cursor[t] = lds[t] - v; }
    if (t == nbc - 1) starts[nbc] = lds[t];   // total
}

// staged scatter: CH edges/block; decode ONCE into regs; LDS-bin by bucket;
// reserve contiguous span; run-wise line-pure copy-out
__global__ __launch_bounds__(1024) void scatter_kernel(
    const int* __restrict__ ei1, const float* __restrict__ ew1,
    const int* __restrict__ ei2, const float* __restrict__ ew2,
    int E1, int E2, int nranges, int nbc,
    int* __restrict__ cursor, int2* __restrict__ entries) {
    __shared__ int lstart[MAXB];
    __shared__ int lcur[MAXB];
    __shared__ int gbase[MAXB];
    __shared__ int2 ebuf[CH];
    __shared__ unsigned short ebkt[CH];

    const int t = threadIdx.x;
    const int Etot = E1 + E2;
    const int c0 = blockIdx.x * CH;
    const int cnt = min(CH, Etot - c0);

    // decode once into registers (4 edges/thread, static-indexed)
    int   eb[4], epk[4];
    float ewt[4];
#pragma unroll
    for (int i = 0; i < 4; ++i) {
        const int idx = t + i * SCT;
        eb[i] = 0; epk[i] = 0; ewt[i] = 0.f;
        if (idx < cnt) {
            int b, src, dl; float w;
            decode_edge(c0 + idx, ei1, ew1, ei2, ew2, E1, E2, nranges, b, src, w, dl);
            eb[i]  = b;
            epk[i] = src | (dl << 17);
            ewt[i] = w;
        }
    }

    for (int i = t; i < nbc; i += SCT) lcur[i] = 0;
    __syncthreads();
#pragma unroll
    for (int i = 0; i < 4; ++i) {
        const int idx = t + i * SCT;
        if (idx < cnt) atomicAdd(&lcur[eb[i]], 1);
    }
    __syncthreads();
    int v = (t < nbc) ? lcur[t] : 0;
    lstart[t] = v;
    __syncthreads();
    for (int off = 1; off < SCT; off <<= 1) {
        int add = (t >= off) ? lstart[t - off] : 0;
        __syncthreads();
        lstart[t] += add;
        __syncthreads();
    }
    int ex = lstart[t] - v;
    __syncthreads();
    if (t < nbc) {
        lstart[t] = ex;
        lcur[t]   = ex;
        gbase[t]  = v ? atomicAdd(&cursor[t], v) : 0;
    }
    __syncthreads();
#pragma unroll
    for (int i = 0; i < 4; ++i) {
        const int idx = t + i * SCT;
        if (idx < cnt) {
            int pos = atomicAdd(&lcur[eb[i]], 1);
            ebuf[pos] = make_int2(epk[i], __float_as_int(ewt[i]));
            ebkt[pos] = (unsigned short)eb[i];
        }
    }
    __syncthreads();
    for (int i = t; i < cnt; i += SCT) {
        int b = ebkt[i];
        entries[gbase[b] + (i - lstart[b])] = ebuf[i];
    }
}

// gather: one block per bucket. Per 4096-entry chunk: LDS counting-sort by dl,
// then wave wv accumulates nodes [16wv,16wv+16) into 16 static VGPRs.
// Inner loop: the round-7 champion form (single entry, unroll 4) — beats all
// restructures tried (pairing/predication/unroll-8 each lost >=25%).
__global__ __launch_bounds__(1024, 8) void gather_kernel(
    const int2* __restrict__ entries, const int* __restrict__ starts,
    const unsigned short* __restrict__ xb, float* __restrict__ out,
    int N, int nranges) {
    __shared__ int2 sbuf[GCH];      // 32 KB sorted chunk
    __shared__ int shist[RSZ];
    __shared__ int sstart[RSZ];
    __shared__ int scur[RSZ];

    const int t    = threadIdx.x;
    const int lane = t & 63;
    const int wv   = t >> 6;        // 0..15
    // schedule heavy hop-2 buckets first
    const int c    = (blockIdx.x < nranges) ? (nranges + blockIdx.x)
                                            : (blockIdx.x - nranges);
    const int hop  = (c >= nranges) ? 1 : 0;
    const int r0   = (c - hop * nranges) << RB;

    const int s = starts[c];
    const int e = starts[c + 1];

    float acc[16];
#pragma unroll
    for (int i = 0; i < 16; ++i) acc[i] = 0.f;

    for (int cb = s; cb < e; cb += GCH) {
        const int cnt = min(GCH, e - cb);
        if (t < RSZ) shist[t] = 0;
        __syncthreads();

        int2 ent[4];
#pragma unroll
        for (int i = 0; i < 4; ++i) {
            const int idx = t + i * 1024;
            if (idx < cnt) {
                ent[i] = entries[cb + idx];
                atomicAdd(&shist[(ent[i].x >> 17) & (RSZ - 1)], 1);
            }
        }
        __syncthreads();

        if (t < RSZ) sstart[t] = shist[t];
        __syncthreads();
        for (int off = 1; off < RSZ; off <<= 1) {
            int v = 0;
            if (t < RSZ && t >= off) v = sstart[t - off];
            __syncthreads();
            if (t < RSZ) sstart[t] += v;
            __syncthreads();
        }
        if (t < RSZ) { int ex = sstart[t] - shist[t]; sstart[t] = ex; scur[t] = ex; }
        __syncthreads();

#pragma unroll
        for (int i = 0; i < 4; ++i) {
            const int idx = t + i * 1024;
            if (idx < cnt) {
                int pos = atomicAdd(&scur[(ent[i].x >> 17) & (RSZ - 1)], 1);
                sbuf[pos] = ent[i];
            }
        }
        __syncthreads();

        // per-wave gather: dense sorted runs, register accumulation
#pragma unroll
        for (int nl = 0; nl < 16; ++nl) {
            const int dl = (wv << 4) + nl;
            const int js = sstart[dl];
            const int je = js + shist[dl];
            float a = acc[nl];
#pragma unroll 4
            for (int j = js; j < je; ++j) {
                const int2 q  = sbuf[j];               // uniform addr: broadcast
                const float w = __int_as_float(q.y);
                const int src = q.x & 0x1FFFF;
                const unsigned xv = xb[src * D + lane];  // coalesced 128B row
                a += w * __uint_as_float(xv << 16);      // bf16 -> f32 = shl 16
            }
            acc[nl] = a;
        }
        __syncthreads();   // protect sbuf/shist before next chunk
    }

#pragma unroll
    for (int nl = 0; nl < 16; ++nl) {
        const int node = r0 + (wv << 4) + nl;
        if (node < N) out[node * 2 * D + hop * D + lane] = acc[nl];
    }
}

extern "C" void kernel_launch(void* const* d_in, const int* in_sizes, int n_in,
                              void* d_out, int out_size, void* d_ws, size_t ws_size,
                              hipStream_t stream) {
    const float* x   = (const float*)d_in[0];
    const int*   ei1 = (const int*)d_in[1];
    const float* ew1 = (const float*)d_in[2];
    const int*   ei2 = (const int*)d_in[3];
    const float* ew2 = (const float*)d_in[4];

    const int E1 = in_sizes[2];
    const int E2 = in_sizes[4];
    const int N  = in_sizes[0] / D;
    const int Etot = E1 + E2;
    const int nranges = (N + RSZ - 1) >> RB;
    const int nbc = 2 * nranges;     // hop-major buckets (need 782)

    float* out = (float*)d_out;

    // ws layout: entries [Etot int2] | xb [N*D ushort] | counts | starts | cursor
    size_t off_entries = 0;
    size_t off_xb      = off_entries + (size_t)Etot * sizeof(int2);
    size_t off_counts  = off_xb + (((size_t)N * D * sizeof(unsigned short) + 15) & ~15ull);
    size_t off_starts  = off_counts + (size_t)nbc * sizeof(int);
    size_t off_cursor  = off_starts + (size_t)(nbc + 1) * sizeof(int);
    size_t needed      = off_cursor + (size_t)nbc * sizeof(int);

    if (ws_size < needed || nbc > MAXB || N > (1 << 17) || (N * D) % 4 != 0) {
        hipMemsetAsync(d_out, 0, (size_t)out_size * sizeof(float), stream);
        spmm_atomic_kernel<<<2048, 256, 0, stream>>>(ei1, ew1, x, out, E1, 0);
        spmm_atomic_kernel<<<2048, 256, 0, stream>>>(ei2, ew2, x, out, E2, D);
        return;
    }

    char* ws = (char*)d_ws;
    int2*           entries = (int2*)(ws + off_entries);
    unsigned short* xbuf    = (unsigned short*)(ws + off_xb);
    int*            counts  = (int*)(ws + off_counts);
    int*            starts  = (int*)(ws + off_starts);
    int*            cursor  = (int*)(ws + off_cursor);

    hipMemsetAsync(counts, 0, (size_t)nbc * sizeof(int), stream);

    const int total4 = (N * D) / 4;
    const int cvtBlocks = (total4 + 255) / 256;
    prep_kernel<<<cvtBlocks + 1024, 256, 0, stream>>>(
        x, xbuf, total4, ei1, ei2, E1, E2, nranges, nbc, counts, cvtBlocks);
    scan_kernel<<<1, 1024, 0, stream>>>(counts, nbc, starts, cursor);
    const int nchunks = (Etot + CH - 1) / CH;
    scatter_kernel<<<nchunks, SCT, 0, stream>>>(ei1, ew1, ei2, ew2, E1, E2,
                                                nranges, nbc, cursor, entries);
    gather_kernel<<<nbc, 1024, 0, stream>>>(entries, starts, xbuf, out, N, nranges);
}